// Round 1
// baseline (1453.654 us; speedup 1.0000x reference)
//
#include <hip/hip_runtime.h>
#include <stdint.h>

#define HIDDEN 4096
#define NHEADS 32
#define HD 128
#define SEQ 2048
#define NTOK 4096
#define QKVN 12288

typedef __attribute__((ext_vector_type(8))) short frag8;
typedef __attribute__((ext_vector_type(4))) float fl4;

__device__ __forceinline__ unsigned short f2b(float f) {
    unsigned u = __float_as_uint(f);
    return (unsigned short)((u + 0x7FFFu + ((u >> 16) & 1u)) >> 16);
}
__device__ __forceinline__ float b2f(unsigned short h) {
    return __uint_as_float(((unsigned)h) << 16);
}
// async global->LDS, 16B per lane. LDS dest is wave-uniform base + lane*16.
__device__ __forceinline__ void gl_lds16(const void* g, void* l) {
    __builtin_amdgcn_global_load_lds(
        (const __attribute__((address_space(1))) unsigned int*)(uintptr_t)g,
        (__attribute__((address_space(3))) unsigned int*)(uintptr_t)l,
        16, 0, 0);
}

// ---------------- fp32 -> bf16 conversion ----------------
__global__ void cvt_f32_bf16(const float* __restrict__ src,
                             unsigned short* __restrict__ dst, int n8) {
    int i = blockIdx.x * 256 + threadIdx.x;
    if (i >= n8) return;
    long e = (long)i * 8;
    fl4 a = *(const fl4*)(src + e);
    fl4 b = *(const fl4*)(src + e + 4);
    union { unsigned short us[8]; frag8 v; } o;
    o.us[0] = f2b(a[0]); o.us[1] = f2b(a[1]); o.us[2] = f2b(a[2]); o.us[3] = f2b(a[3]);
    o.us[4] = f2b(b[0]); o.us[5] = f2b(b[1]); o.us[6] = f2b(b[2]); o.us[7] = f2b(b[3]);
    *(frag8*)(dst + e) = o.v;
}

// ---------------- RoPE (in-place on q,k regions of proj) ----------------
__global__ void rope_kernel(unsigned short* __restrict__ proj,
                            const int* __restrict__ positions) {
    int tid = blockIdx.x * 256 + threadIdx.x;   // one thread per rotation pair
    int j  = tid & 63;
    int h  = (tid >> 6) & 31;
    int qk = (tid >> 11) & 1;
    int t  = tid >> 12;                          // token index 0..4095
    int pos = positions[t];
    float inv = powf(10000.0f, -(float)j * (1.0f / 64.0f));
    float fr = (float)pos * inv;
    float sv, cv;
    sincosf(fr, &sv, &cv);
    unsigned short* base = proj + (long)t * QKVN + qk * HIDDEN + h * HD;
    float x1 = b2f(base[j]);
    float x2 = b2f(base[j + 64]);
    base[j]      = f2b(x1 * cv - x2 * sv);
    base[j + 64] = f2b(x2 * cv + x1 * sv);
}

// ---------------- GEMM: C[M,N] = A[M,K] * B[N,K]^T (bf16 in, fp32 acc) --------
// m97 structure: 128x128 tile, BK=32, 4 waves (2x2), 4x4 16x16 subtiles/wave,
// global_load_lds width 16, XOR k-chunk swizzle to kill LDS bank conflicts.
template <int OUT_F32>
__global__ __launch_bounds__(256) void gemm_bt(
    const unsigned short* __restrict__ A,
    const unsigned short* __restrict__ B,
    void* __restrict__ Cv, int M, int N, int K) {
    __shared__ unsigned short As[128 * 32];
    __shared__ unsigned short Bs[128 * 32];
    const int tid  = threadIdx.x;
    const int lane = tid & 63;
    const int w    = tid >> 6;
    const long m0 = (long)blockIdx.y * 128;
    const long n0 = (long)blockIdx.x * 128;
    // staging: lane covers row srow (+0/+64), 8 bf16 (16B) chunk. LDS layout is
    // forced row-major (base + lane*16); the XOR permutes which logical k-chunk
    // lands in each physical slot: phys[r][c] = logical[r][c ^ ((r>>1)&3)].
    const int srow = w * 16 + (lane >> 2);
    const int pcol = (lane & 3) * 8;
    const int gcol = ((lane & 3) ^ ((lane >> 3) & 3)) * 8;
    const unsigned short* gA0 = A + (m0 + srow) * K + gcol;
    const unsigned short* gA1 = A + (m0 + 64 + srow) * K + gcol;
    const unsigned short* gB0 = B + (n0 + srow) * K + gcol;
    const unsigned short* gB1 = B + (n0 + 64 + srow) * K + gcol;
    unsigned short* lA0 = As + srow * 32 + pcol;
    unsigned short* lA1 = As + (64 + srow) * 32 + pcol;
    unsigned short* lB0 = Bs + srow * 32 + pcol;
    unsigned short* lB1 = Bs + (64 + srow) * 32 + pcol;

    const int wm = (w >> 1) * 64, wn = (w & 1) * 64;
    const int fr = lane & 15;
    const int quad = lane >> 4;
    const int axk = (quad ^ ((fr >> 1) & 3)) * 8;  // phys chunk for frag reads

    fl4 acc[4][4];
    fl4 z = {0.f, 0.f, 0.f, 0.f};
#pragma unroll
    for (int i = 0; i < 4; i++)
#pragma unroll
        for (int j = 0; j < 4; j++) acc[i][j] = z;

    for (int kt = 0; kt < K; kt += 32) {
        __syncthreads();
        gl_lds16(gA0 + kt, lA0);
        gl_lds16(gA1 + kt, lA1);
        gl_lds16(gB0 + kt, lB0);
        gl_lds16(gB1 + kt, lB1);
        __syncthreads();
        frag8 af[4], bf[4];
#pragma unroll
        for (int mi = 0; mi < 4; mi++)
            af[mi] = *(const frag8*)(As + (wm + mi * 16 + fr) * 32 + axk);
#pragma unroll
        for (int ni = 0; ni < 4; ni++)
            bf[ni] = *(const frag8*)(Bs + (wn + ni * 16 + fr) * 32 + axk);
#pragma unroll
        for (int mi = 0; mi < 4; mi++)
#pragma unroll
            for (int ni = 0; ni < 4; ni++)
                acc[mi][ni] = __builtin_amdgcn_mfma_f32_16x16x32_bf16(
                    af[mi], bf[ni], acc[mi][ni], 0, 0, 0);
    }
    const int q4 = quad * 4;
#pragma unroll
    for (int mi = 0; mi < 4; mi++)
#pragma unroll
        for (int ni = 0; ni < 4; ni++)
#pragma unroll
            for (int r = 0; r < 4; r++) {
                long row = m0 + wm + mi * 16 + q4 + r;
                long col = n0 + wn + ni * 16 + fr;
                float v = acc[mi][ni][r];
                if (OUT_F32)
                    ((float*)Cv)[row * N + col] = v;
                else
                    ((unsigned short*)Cv)[row * N + col] = f2b(v);
            }
}

// ---------------- causal flash attention ----------------
// block = (q-tile of 128) x head x batch; 4 waves, each owns 32 q rows.
// K-tile = 64 keys/iter. Q frags live in registers (loaded once from global).
__global__ __launch_bounds__(256, 2) void attn_kernel(
    const unsigned short* __restrict__ proj,   // [NTOK, 12288], rope'd
    unsigned short* __restrict__ out) {        // [NTOK, 4096]
    __shared__ unsigned short Ks[64 * 128];    // [k][d], XOR chunk swizzle
    __shared__ unsigned short Vt[128 * 80];    // [d][k], stride 80
    __shared__ unsigned short Ps[4][32 * 88];  // per-wave P, stride 88

    const int qt = (int)gridDim.x - 1 - (int)blockIdx.x;  // big tiles first
    const int h = blockIdx.y;
    const int b = blockIdx.z;
    const int tid = threadIdx.x, lane = tid & 63, w = tid >> 6;
    const int q0 = qt * 128;
    const int fr = lane & 15, quad = lane >> 4;
    const int fq = quad * 8;
    const long tokbase = (long)b * SEQ;
    const float scale = 0.08838834764831845f;  // 1/sqrt(128)
    fl4 z = {0.f, 0.f, 0.f, 0.f};

    // Q fragments (A-layout): rows q0 + w*32 + mi*16 + fr
    frag8 qf[2][4];
#pragma unroll
    for (int mi = 0; mi < 2; mi++)
#pragma unroll
        for (int kc = 0; kc < 4; kc++) {
            int qrow = q0 + w * 32 + mi * 16 + fr;
            qf[mi][kc] = *(const frag8*)(proj + (tokbase + qrow) * QKVN +
                                         h * HD + kc * 32 + fq);
        }

    fl4 o[2][8];
#pragma unroll
    for (int mi = 0; mi < 2; mi++)
#pragma unroll
        for (int n = 0; n < 8; n++) o[mi][n] = z;
    float m_i[2][4], l_i[2][4];
#pragma unroll
    for (int mi = 0; mi < 2; mi++)
#pragma unroll
        for (int r = 0; r < 4; r++) { m_i[mi][r] = -1e30f; l_i[mi][r] = 0.f; }

    // K staging: LDS row = c*16 + w*4 + (lane>>4); phys chunk lane&15;
    // XOR swizzle phys[r][c] = logical[r][c ^ (r&15)]
    const int ksrow = w * 4 + (lane >> 4);
    const int kphys = (lane & 15) * 8;
    const int kgcol = ((lane & 15) ^ ksrow) * 8;
    // V staging (transpose): thread -> (row=lane, dchunk=w*32)
    const int vrow = lane;
    const int vdc = w * 32;

    const int ktiles = (q0 + 128) / 64;
    for (int kt = 0; kt < ktiles; kt++) {
        const int k0 = kt * 64;
        __syncthreads();
#pragma unroll
        for (int c = 0; c < 4; c++) {
            long tok = tokbase + k0 + c * 16 + ksrow;
            gl_lds16(proj + tok * QKVN + HIDDEN + h * HD + kgcol,
                     Ks + (c * 16 + ksrow) * 128 + kphys);
        }
        {
            const unsigned short* vp =
                proj + (tokbase + k0 + vrow) * QKVN + 2 * HIDDEN + h * HD + vdc;
#pragma unroll
            for (int u = 0; u < 4; u++) {
                frag8 vv = *(const frag8*)(vp + u * 8);
#pragma unroll
                for (int e = 0; e < 8; e++)
                    Vt[(vdc + u * 8 + e) * 80 + vrow] = (unsigned short)vv[e];
            }
        }
        __syncthreads();

        // S = Q K^T
        fl4 sc[2][4];
#pragma unroll
        for (int kn = 0; kn < 4; kn++) {
            frag8 kf[4];
#pragma unroll
            for (int kc = 0; kc < 4; kc++)
                kf[kc] = *(const frag8*)(Ks + (kn * 16 + fr) * 128 +
                                         ((kc * 4 + quad) ^ fr) * 8);
#pragma unroll
            for (int mi = 0; mi < 2; mi++) {
                fl4 a = z;
#pragma unroll
                for (int kc = 0; kc < 4; kc++)
                    a = __builtin_amdgcn_mfma_f32_16x16x32_bf16(qf[mi][kc],
                                                                kf[kc], a, 0, 0, 0);
                sc[mi][kn] = a;
            }
        }
        // online softmax (rows = quad*4+r per C-layout)
#pragma unroll
        for (int mi = 0; mi < 2; mi++) {
#pragma unroll
            for (int r = 0; r < 4; r++) {
                int qrow = q0 + w * 32 + mi * 16 + quad * 4 + r;
                float sv4[4];
                float mx = -1e30f;
#pragma unroll
                for (int kn = 0; kn < 4; kn++) {
                    int kcol = k0 + kn * 16 + fr;
                    float s = sc[mi][kn][r] * scale;
                    s = (kcol <= qrow) ? s : -1e30f;
                    sv4[kn] = s;
                    mx = fmaxf(mx, s);
                }
#pragma unroll
                for (int off = 1; off < 16; off <<= 1)
                    mx = fmaxf(mx, __shfl_xor(mx, off, 64));
                float mold = m_i[mi][r];
                float mnew = fmaxf(mold, mx);
                float alpha = __expf(mold - mnew);
                float rsum = 0.f;
#pragma unroll
                for (int kn = 0; kn < 4; kn++) {
                    float p = __expf(sv4[kn] - mnew);
                    unsigned short pb = f2b(p);
                    Ps[w][(mi * 16 + quad * 4 + r) * 88 + kn * 16 + fr] = pb;
                    rsum += b2f(pb);
                }
#pragma unroll
                for (int off = 1; off < 16; off <<= 1)
                    rsum += __shfl_xor(rsum, off, 64);
                l_i[mi][r] = l_i[mi][r] * alpha + rsum;
                m_i[mi][r] = mnew;
#pragma unroll
                for (int n = 0; n < 8; n++) o[mi][n][r] *= alpha;
            }
        }
        // O += P V   (P round-trips LDS: C-layout -> A-layout; per-wave, no barrier)
        frag8 pf[2][2];
#pragma unroll
        for (int mi = 0; mi < 2; mi++)
#pragma unroll
            for (int kc = 0; kc < 2; kc++)
                pf[mi][kc] =
                    *(const frag8*)(Ps[w] + (mi * 16 + fr) * 88 + kc * 32 + fq);
#pragma unroll
        for (int n = 0; n < 8; n++) {
            frag8 vf0 = *(const frag8*)(Vt + (n * 16 + fr) * 80 + fq);
            frag8 vf1 = *(const frag8*)(Vt + (n * 16 + fr) * 80 + 32 + fq);
#pragma unroll
            for (int mi = 0; mi < 2; mi++) {
                o[mi][n] = __builtin_amdgcn_mfma_f32_16x16x32_bf16(pf[mi][0], vf0,
                                                                   o[mi][n], 0, 0, 0);
                o[mi][n] = __builtin_amdgcn_mfma_f32_16x16x32_bf16(pf[mi][1], vf1,
                                                                   o[mi][n], 0, 0, 0);
            }
        }
    }
    // epilogue: O / l -> out[tok][h*128 + d]
#pragma unroll
    for (int mi = 0; mi < 2; mi++)
#pragma unroll
        for (int n = 0; n < 8; n++)
#pragma unroll
            for (int r = 0; r < 4; r++) {
                int qrow = q0 + w * 32 + mi * 16 + quad * 4 + r;
                float val = o[mi][n][r] / l_i[mi][r];
                out[(tokbase + qrow) * HIDDEN + h * HD + n * 16 + fr] = f2b(val);
            }
}

extern "C" void kernel_launch(void* const* d_in, const int* in_sizes, int n_in,
                              void* d_out, int out_size, void* d_ws, size_t ws_size,
                              hipStream_t stream) {
    const float* hs = (const float*)d_in[0];   // [2,2048,4096]
    const int* pos  = (const int*)d_in[1];     // [2,2048]
    const float* wp = (const float*)d_in[2];   // [12288,4096]
    const float* wo = (const float*)d_in[3];   // [4096,4096]
    float* out = (float*)d_out;                // [2,2048,4096] fp32

    char* ws = (char*)d_ws;
    unsigned short* Xb    = (unsigned short*)ws;                 // 32 MB
    unsigned short* Wpb   = (unsigned short*)(ws + 33554432L);   // 96 MB
    unsigned short* proj  = (unsigned short*)(ws + 134217728L);  // 96 MB
    unsigned short* attnb = Wpb;  // reuse after gemm1
    unsigned short* Wob   = Xb;   // reuse after gemm1

    cvt_f32_bf16<<<(16777216 / 8) / 256, 256, 0, stream>>>(hs, Xb, 16777216 / 8);
    cvt_f32_bf16<<<(50331648 / 8) / 256, 256, 0, stream>>>(wp, Wpb, 50331648 / 8);
    gemm_bt<0><<<dim3(QKVN / 128, NTOK / 128), 256, 0, stream>>>(
        Xb, Wpb, (void*)proj, NTOK, QKVN, HIDDEN);
    rope_kernel<<<16777216 / 256, 256, 0, stream>>>(proj, pos);
    attn_kernel<<<dim3(SEQ / 128, NHEADS, 2), 256, 0, stream>>>(proj, attnb);
    cvt_f32_bf16<<<(16777216 / 8) / 256, 256, 0, stream>>>(wo, Wob, 16777216 / 8);
    gemm_bt<1><<<dim3(HIDDEN / 128, NTOK / 128), 256, 0, stream>>>(
        attnb, Wob, d_out, NTOK, HIDDEN, HIDDEN);
}

// Round 2
// 1200.944 us; speedup vs baseline: 1.2104x; 1.2104x over previous
//
#include <hip/hip_runtime.h>
#include <stdint.h>

#define HIDDEN 4096
#define NHEADS 32
#define HD 128
#define SEQ 2048
#define NTOK 4096
#define QKVN 12288

typedef __attribute__((ext_vector_type(8))) short frag8;
typedef __attribute__((ext_vector_type(4))) float fl4;

__device__ __forceinline__ unsigned short f2b(float f) {
    unsigned u = __float_as_uint(f);
    return (unsigned short)((u + 0x7FFFu + ((u >> 16) & 1u)) >> 16);
}
__device__ __forceinline__ float b2f(unsigned short h) {
    return __uint_as_float(((unsigned)h) << 16);
}
// async global->LDS, 16B per lane. LDS dest is wave-uniform base + lane*16.
__device__ __forceinline__ void gl_lds16(const void* g, void* l) {
    __builtin_amdgcn_global_load_lds(
        (const __attribute__((address_space(1))) unsigned int*)(uintptr_t)g,
        (__attribute__((address_space(3))) unsigned int*)(uintptr_t)l,
        16, 0, 0);
}

// ---------------- fp32 -> bf16 conversion ----------------
__global__ void cvt_f32_bf16(const float* __restrict__ src,
                             unsigned short* __restrict__ dst, int n8) {
    int i = blockIdx.x * 256 + threadIdx.x;
    if (i >= n8) return;
    long e = (long)i * 8;
    fl4 a = *(const fl4*)(src + e);
    fl4 b = *(const fl4*)(src + e + 4);
    union { unsigned short us[8]; frag8 v; } o;
    o.us[0] = f2b(a[0]); o.us[1] = f2b(a[1]); o.us[2] = f2b(a[2]); o.us[3] = f2b(a[3]);
    o.us[4] = f2b(b[0]); o.us[5] = f2b(b[1]); o.us[6] = f2b(b[2]); o.us[7] = f2b(b[3]);
    *(frag8*)(dst + e) = o.v;
}

// ---------------- RoPE (in-place on q,k regions of proj) ----------------
__global__ void rope_kernel(unsigned short* __restrict__ proj,
                            const int* __restrict__ positions) {
    int tid = blockIdx.x * 256 + threadIdx.x;   // one thread per rotation pair
    int j  = tid & 63;
    int h  = (tid >> 6) & 31;
    int qk = (tid >> 11) & 1;
    int t  = tid >> 12;                          // token index 0..4095
    int pos = positions[t];
    float inv = powf(10000.0f, -(float)j * (1.0f / 64.0f));
    float fr = (float)pos * inv;
    float sv, cv;
    sincosf(fr, &sv, &cv);
    unsigned short* base = proj + (long)t * QKVN + qk * HIDDEN + h * HD;
    float x1 = b2f(base[j]);
    float x2 = b2f(base[j + 64]);
    base[j]      = f2b(x1 * cv - x2 * sv);
    base[j + 64] = f2b(x2 * cv + x1 * sv);
}

// ---------------- GEMM 256x256, BK=64, 8-phase counted-vmcnt pipeline -------
// C[M,N] = A[M,K] * B[N,K]^T, bf16 in, fp32 acc.
// 8 waves (2M x 4N), per-wave 128x64 output. LDS 128 KiB: 2 dbuf x (A 2 halves
// + B 2 halves) of [128][64] bf16. 3-bit XOR swizzle u ^= ((u>>6)&7)<<3 within
// each half (involution): applied as inverse-swizzled global SOURCE for the
// linear global_load_lds dest, and as swizzled ds_read offsets.
// Schedule per K-tile T (4 phases; 2 tiles unrolled = 8 phases/iter):
//  ph1: read A-h0 + B-h0 frags | stage a1(T+1)->other buf | bar; lgkm0; 16 MFMA; bar
//  ph2: read B-h1 frags        | stage a0(T+2)->this buf  | bar; lgkm0; 16 MFMA; bar
//  ph3: read A-h1 frags        | stage b0(T+2)            | bar; lgkm0; 16 MFMA; bar
//  ph4:                          stage b1(T+2) | vmcnt(6) | bar; 16 MFMA; bar
// vmcnt(6) = 2 loads/half x 3 halves in flight; never drains to 0 in the loop.
template <int OUT_F32>
__global__ __launch_bounds__(512, 2) void gemm256(
    const unsigned short* __restrict__ A,
    const unsigned short* __restrict__ B,
    void* __restrict__ Cv, int M, int N, int K) {
    __shared__ unsigned short lds[65536];  // 128 KiB
    const int tid = threadIdx.x, lane = tid & 63, w = tid >> 6;
    const int wr = w >> 2, wc = w & 3;
    const int fr = lane & 15, quad = lane >> 4;

    // XCD-aware bijective swizzle (nwg % 8 == 0 for both call sites)
    const int gx = gridDim.x;
    const int nwg = gx * gridDim.y;
    int bid = blockIdx.y * gx + blockIdx.x;
    const int cpx = nwg >> 3;
    int swz = (bid & 7) * cpx + (bid >> 3);
    const long n0 = (long)(swz % gx) * 256;
    const long m0 = (long)(swz / gx) * 256;

    // --- staging (inverse-swizzled global source, linear LDS dest) ---
    const int r0 = w * 8 + (lane >> 3);                  // row within 128-half, l=0
    const int scol = ((lane ^ (lane >> 3)) & 7) * 8;     // swizzled k-col (bf16)
    const int dofs = w * 512 + lane * 8;                 // ushort off within half
    const unsigned short* Ag = A + (m0 + r0) * (long)K + scol;
    const unsigned short* Bg = B + (n0 + r0) * (long)K + scol;
    auto stg = [&](unsigned short* Lh, const unsigned short* G, long t) {
        gl_lds16(G + t * 64, Lh + dofs);
        gl_lds16(G + t * 64 + (long)K * 64, Lh + dofs + 4096);
    };
#define STGA(s, h, t) stg(lds + (s)*32768 + (h)*8192, Ag + (long)(h) * 128 * K, (t))
#define STGB(s, h, t) stg(lds + (s)*32768 + 16384 + (h)*8192, Bg + (long)(h) * 128 * K, (t))

    // --- fragment read offsets (swizzled) ---
    const int qx8 = (quad ^ (fr & 3)) * 8;
    const int kx0 = (fr >> 2) & 1;
    const int arow = wr * 64 + fr;   // + mi*16 within A-half
    const int brow = wc * 32 + fr;   // + ni*16 within B-half

    frag8 af[4][2], bf0[2][2], bf1[2][2];
    fl4 acc[2][2][4][2];
    fl4 z = {0.f, 0.f, 0.f, 0.f};
#pragma unroll
    for (int qm = 0; qm < 2; ++qm)
#pragma unroll
        for (int qn = 0; qn < 2; ++qn)
#pragma unroll
            for (int mi = 0; mi < 4; ++mi)
#pragma unroll
                for (int ni = 0; ni < 2; ++ni) acc[qm][qn][mi][ni] = z;

#define LDA(h)                                                                   \
    _Pragma("unroll") for (int mi = 0; mi < 4; ++mi) {                           \
        af[mi][0] = *(const frag8*)(Lc + (h)*8192 + (arow + mi * 16) * 64 +      \
                                    (kx0 << 5) + qx8);                           \
        af[mi][1] = *(const frag8*)(Lc + (h)*8192 + (arow + mi * 16) * 64 +      \
                                    ((1 ^ kx0) << 5) + qx8);                     \
    }
#define LDB(h, BF)                                                               \
    _Pragma("unroll") for (int ni = 0; ni < 2; ++ni) {                           \
        BF[ni][0] = *(const frag8*)(Lc + 16384 + (h)*8192 +                      \
                                    (brow + ni * 16) * 64 + (kx0 << 5) + qx8);   \
        BF[ni][1] = *(const frag8*)(Lc + 16384 + (h)*8192 +                      \
                                    (brow + ni * 16) * 64 + ((1 ^ kx0) << 5) +   \
                                    qx8);                                        \
    }
#define MF(qm, qn, BF)                                                           \
    __builtin_amdgcn_s_setprio(1);                                               \
    _Pragma("unroll") for (int mi = 0; mi < 4; ++mi)                             \
        _Pragma("unroll") for (int ni = 0; ni < 2; ++ni) {                       \
        acc[qm][qn][mi][ni] = __builtin_amdgcn_mfma_f32_16x16x32_bf16(           \
            af[mi][0], BF[ni][0], acc[qm][qn][mi][ni], 0, 0, 0);                 \
        acc[qm][qn][mi][ni] = __builtin_amdgcn_mfma_f32_16x16x32_bf16(           \
            af[mi][1], BF[ni][1], acc[qm][qn][mi][ni], 0, 0, 0);                 \
    }                                                                            \
    __builtin_amdgcn_s_setprio(0);

#define KTILE(s, T)                                                              \
    {                                                                            \
        unsigned short* Lc = lds + (s)*32768;                                    \
        const long t1 = ((T) + 1 < nt) ? (T) + 1 : nt - 1;                       \
        const long t2 = ((T) + 2 < nt) ? (T) + 2 : nt - 1;                       \
        LDA(0);                                                                  \
        LDB(0, bf0);                                                             \
        STGA((s) ^ 1, 1, t1);                                                    \
        __builtin_amdgcn_s_barrier();                                            \
        asm volatile("s_waitcnt lgkmcnt(0)" ::: "memory");                       \
        MF(0, 0, bf0);                                                           \
        __builtin_amdgcn_s_barrier();                                            \
        LDB(1, bf1);                                                             \
        STGA((s), 0, t2);                                                        \
        __builtin_amdgcn_s_barrier();                                            \
        asm volatile("s_waitcnt lgkmcnt(0)" ::: "memory");                       \
        MF(0, 1, bf1);                                                           \
        __builtin_amdgcn_s_barrier();                                            \
        LDA(1);                                                                  \
        STGB((s), 0, t2);                                                        \
        __builtin_amdgcn_s_barrier();                                            \
        asm volatile("s_waitcnt lgkmcnt(0)" ::: "memory");                       \
        MF(1, 0, bf0);                                                           \
        __builtin_amdgcn_s_barrier();                                            \
        STGB((s), 1, t2);                                                        \
        asm volatile("s_waitcnt vmcnt(6)" ::: "memory");                         \
        __builtin_amdgcn_s_barrier();                                            \
        MF(1, 1, bf1);                                                           \
        __builtin_amdgcn_s_barrier();                                            \
    }

    const int nt = K >> 6;  // K-tiles of 64 (even for all call sites)
    // prologue: tile0 fully + first 3 halves of tile1 (FIFO matches steady state)
    STGA(0, 0, 0);
    STGB(0, 0, 0);
    STGB(0, 1, 0);
    STGA(0, 1, 0);
    STGA(1, 0, 1);
    STGB(1, 0, 1);
    STGB(1, 1, 1);
    asm volatile("s_waitcnt vmcnt(6)" ::: "memory");
    __builtin_amdgcn_s_barrier();

    for (int T = 0; T < nt; T += 2) {
        KTILE(0, T);
        KTILE(1, T + 1);
    }
    asm volatile("s_waitcnt vmcnt(0)" ::: "memory");

    // epilogue: C write
#pragma unroll
    for (int qm = 0; qm < 2; ++qm)
#pragma unroll
        for (int qn = 0; qn < 2; ++qn)
#pragma unroll
            for (int mi = 0; mi < 4; ++mi)
#pragma unroll
                for (int ni = 0; ni < 2; ++ni)
#pragma unroll
                    for (int r = 0; r < 4; ++r) {
                        long row = m0 + qm * 128 + wr * 64 + mi * 16 + quad * 4 + r;
                        long col = n0 + qn * 128 + wc * 32 + ni * 16 + fr;
                        float v = acc[qm][qn][mi][ni][r];
                        if (OUT_F32)
                            ((float*)Cv)[row * N + col] = v;
                        else
                            ((unsigned short*)Cv)[row * N + col] = f2b(v);
                    }
#undef STGA
#undef STGB
#undef LDA
#undef LDB
#undef MF
#undef KTILE
}

// ---------------- causal flash attention ----------------
// block = (q-tile of 128) x head x batch; 4 waves, each owns 32 q rows.
// K-tile = 64 keys/iter. Q frags live in registers (loaded once from global).
__global__ __launch_bounds__(256, 2) void attn_kernel(
    const unsigned short* __restrict__ proj,   // [NTOK, 12288], rope'd
    unsigned short* __restrict__ out) {        // [NTOK, 4096]
    __shared__ unsigned short Ks[64 * 128];    // [k][d], XOR chunk swizzle
    __shared__ unsigned short Vt[128 * 80];    // [d][k], stride 80
    __shared__ unsigned short Ps[4][32 * 88];  // per-wave P, stride 88

    const int qt = (int)gridDim.x - 1 - (int)blockIdx.x;  // big tiles first
    const int h = blockIdx.y;
    const int b = blockIdx.z;
    const int tid = threadIdx.x, lane = tid & 63, w = tid >> 6;
    const int q0 = qt * 128;
    const int fr = lane & 15, quad = lane >> 4;
    const int fq = quad * 8;
    const long tokbase = (long)b * SEQ;
    const float scale = 0.08838834764831845f;  // 1/sqrt(128)
    fl4 z = {0.f, 0.f, 0.f, 0.f};

    // Q fragments (A-layout): rows q0 + w*32 + mi*16 + fr
    frag8 qf[2][4];
#pragma unroll
    for (int mi = 0; mi < 2; mi++)
#pragma unroll
        for (int kc = 0; kc < 4; kc++) {
            int qrow = q0 + w * 32 + mi * 16 + fr;
            qf[mi][kc] = *(const frag8*)(proj + (tokbase + qrow) * QKVN +
                                         h * HD + kc * 32 + fq);
        }

    fl4 o[2][8];
#pragma unroll
    for (int mi = 0; mi < 2; mi++)
#pragma unroll
        for (int n = 0; n < 8; n++) o[mi][n] = z;
    float m_i[2][4], l_i[2][4];
#pragma unroll
    for (int mi = 0; mi < 2; mi++)
#pragma unroll
        for (int r = 0; r < 4; r++) { m_i[mi][r] = -1e30f; l_i[mi][r] = 0.f; }

    // K staging: LDS row = c*16 + w*4 + (lane>>4); phys chunk lane&15;
    // XOR swizzle phys[r][c] = logical[r][c ^ (r&15)]
    const int ksrow = w * 4 + (lane >> 4);
    const int kphys = (lane & 15) * 8;
    const int kgcol = ((lane & 15) ^ ksrow) * 8;
    // V staging (transpose): thread -> (row=lane, dchunk=w*32)
    const int vrow = lane;
    const int vdc = w * 32;

    const int ktiles = (q0 + 128) / 64;
    for (int kt = 0; kt < ktiles; kt++) {
        const int k0 = kt * 64;
        __syncthreads();
#pragma unroll
        for (int c = 0; c < 4; c++) {
            long tok = tokbase + k0 + c * 16 + ksrow;
            gl_lds16(proj + tok * QKVN + HIDDEN + h * HD + kgcol,
                     Ks + (c * 16 + ksrow) * 128 + kphys);
        }
        {
            const unsigned short* vp =
                proj + (tokbase + k0 + vrow) * QKVN + 2 * HIDDEN + h * HD + vdc;
#pragma unroll
            for (int u = 0; u < 4; u++) {
                frag8 vv = *(const frag8*)(vp + u * 8);
#pragma unroll
                for (int e = 0; e < 8; e++)
                    Vt[(vdc + u * 8 + e) * 80 + vrow] = (unsigned short)vv[e];
            }
        }
        __syncthreads();

        // S = Q K^T
        fl4 sc[2][4];
#pragma unroll
        for (int kn = 0; kn < 4; kn++) {
            frag8 kf[4];
#pragma unroll
            for (int kc = 0; kc < 4; kc++)
                kf[kc] = *(const frag8*)(Ks + (kn * 16 + fr) * 128 +
                                         ((kc * 4 + quad) ^ fr) * 8);
#pragma unroll
            for (int mi = 0; mi < 2; mi++) {
                fl4 a = z;
#pragma unroll
                for (int kc = 0; kc < 4; kc++)
                    a = __builtin_amdgcn_mfma_f32_16x16x32_bf16(qf[mi][kc],
                                                                kf[kc], a, 0, 0, 0);
                sc[mi][kn] = a;
            }
        }
        // online softmax (rows = quad*4+r per C-layout)
#pragma unroll
        for (int mi = 0; mi < 2; mi++) {
#pragma unroll
            for (int r = 0; r < 4; r++) {
                int qrow = q0 + w * 32 + mi * 16 + quad * 4 + r;
                float sv4[4];
                float mx = -1e30f;
#pragma unroll
                for (int kn = 0; kn < 4; kn++) {
                    int kcol = k0 + kn * 16 + fr;
                    float s = sc[mi][kn][r] * scale;
                    s = (kcol <= qrow) ? s : -1e30f;
                    sv4[kn] = s;
                    mx = fmaxf(mx, s);
                }
#pragma unroll
                for (int off = 1; off < 16; off <<= 1)
                    mx = fmaxf(mx, __shfl_xor(mx, off, 64));
                float mold = m_i[mi][r];
                float mnew = fmaxf(mold, mx);
                float alpha = __expf(mold - mnew);
                float rsum = 0.f;
#pragma unroll
                for (int kn = 0; kn < 4; kn++) {
                    float p = __expf(sv4[kn] - mnew);
                    unsigned short pb = f2b(p);
                    Ps[w][(mi * 16 + quad * 4 + r) * 88 + kn * 16 + fr] = pb;
                    rsum += b2f(pb);
                }
#pragma unroll
                for (int off = 1; off < 16; off <<= 1)
                    rsum += __shfl_xor(rsum, off, 64);
                l_i[mi][r] = l_i[mi][r] * alpha + rsum;
                m_i[mi][r] = mnew;
#pragma unroll
                for (int n = 0; n < 8; n++) o[mi][n][r] *= alpha;
            }
        }
        // O += P V   (P round-trips LDS: C-layout -> A-layout; per-wave, no barrier)
        frag8 pf[2][2];
#pragma unroll
        for (int mi = 0; mi < 2; mi++)
#pragma unroll
            for (int kc = 0; kc < 2; kc++)
                pf[mi][kc] =
                    *(const frag8*)(Ps[w] + (mi * 16 + fr) * 88 + kc * 32 + fq);
#pragma unroll
        for (int n = 0; n < 8; n++) {
            frag8 vf0 = *(const frag8*)(Vt + (n * 16 + fr) * 80 + fq);
            frag8 vf1 = *(const frag8*)(Vt + (n * 16 + fr) * 80 + 32 + fq);
#pragma unroll
            for (int mi = 0; mi < 2; mi++) {
                o[mi][n] = __builtin_amdgcn_mfma_f32_16x16x32_bf16(pf[mi][0], vf0,
                                                                   o[mi][n], 0, 0, 0);
                o[mi][n] = __builtin_amdgcn_mfma_f32_16x16x32_bf16(pf[mi][1], vf1,
                                                                   o[mi][n], 0, 0, 0);
            }
        }
    }
    // epilogue: O / l -> out[tok][h*128 + d]
#pragma unroll
    for (int mi = 0; mi < 2; mi++)
#pragma unroll
        for (int n = 0; n < 8; n++)
#pragma unroll
            for (int r = 0; r < 4; r++) {
                int qrow = q0 + w * 32 + mi * 16 + quad * 4 + r;
                float val = o[mi][n][r] / l_i[mi][r];
                out[(tokbase + qrow) * HIDDEN + h * HD + n * 16 + fr] = f2b(val);
            }
}

extern "C" void kernel_launch(void* const* d_in, const int* in_sizes, int n_in,
                              void* d_out, int out_size, void* d_ws, size_t ws_size,
                              hipStream_t stream) {
    const float* hs = (const float*)d_in[0];   // [2,2048,4096]
    const int* pos  = (const int*)d_in[1];     // [2,2048]
    const float* wp = (const float*)d_in[2];   // [12288,4096]
    const float* wo = (const float*)d_in[3];   // [4096,4096]
    float* out = (float*)d_out;                // [2,2048,4096] fp32

    char* ws = (char*)d_ws;
    unsigned short* Xb    = (unsigned short*)ws;                 // 32 MB
    unsigned short* Wpb   = (unsigned short*)(ws + 33554432L);   // 96 MB
    unsigned short* proj  = (unsigned short*)(ws + 134217728L);  // 96 MB
    unsigned short* attnb = Wpb;  // reuse after gemm1
    unsigned short* Wob   = Xb;   // reuse after gemm1

    cvt_f32_bf16<<<(16777216 / 8) / 256, 256, 0, stream>>>(hs, Xb, 16777216 / 8);
    cvt_f32_bf16<<<(50331648 / 8) / 256, 256, 0, stream>>>(wp, Wpb, 50331648 / 8);
    gemm256<0><<<dim3(QKVN / 256, NTOK / 256), 512, 0, stream>>>(
        Xb, Wpb, (void*)proj, NTOK, QKVN, HIDDEN);
    rope_kernel<<<16777216 / 256, 256, 0, stream>>>(proj, pos);
    attn_kernel<<<dim3(SEQ / 128, NHEADS, 2), 256, 0, stream>>>(proj, attnb);
    cvt_f32_bf16<<<(16777216 / 8) / 256, 256, 0, stream>>>(wo, Wob, 16777216 / 8);
    gemm256<1><<<dim3(HIDDEN / 256, NTOK / 256), 512, 0, stream>>>(
        attnb, Wob, d_out, NTOK, HIDDEN, HIDDEN);
}

// Round 4
// 1091.445 us; speedup vs baseline: 1.3319x; 1.1003x over previous
//
#include <hip/hip_runtime.h>
#include <stdint.h>

#define HIDDEN 4096
#define NHEADS 32
#define HD 128
#define SEQ 2048
#define NTOK 4096
#define QKVN 12288

typedef __attribute__((ext_vector_type(8))) short frag8;
typedef __attribute__((ext_vector_type(4))) float fl4;

__device__ __forceinline__ unsigned short f2b(float f) {
    unsigned u = __float_as_uint(f);
    return (unsigned short)((u + 0x7FFFu + ((u >> 16) & 1u)) >> 16);
}
__device__ __forceinline__ float b2f(unsigned short h) {
    return __uint_as_float(((unsigned)h) << 16);
}
// async global->LDS, 16B per lane. LDS dest is wave-uniform base + lane*16.
__device__ __forceinline__ void gl_lds16(const void* g, void* l) {
    __builtin_amdgcn_global_load_lds(
        (const __attribute__((address_space(1))) unsigned int*)(uintptr_t)g,
        (__attribute__((address_space(3))) unsigned int*)(uintptr_t)l,
        16, 0, 0);
}

// ---------------- fp32 -> bf16 conversion ----------------
__global__ void cvt_f32_bf16(const float* __restrict__ src,
                             unsigned short* __restrict__ dst, int n8) {
    int i = blockIdx.x * 256 + threadIdx.x;
    if (i >= n8) return;
    long e = (long)i * 8;
    fl4 a = *(const fl4*)(src + e);
    fl4 b = *(const fl4*)(src + e + 4);
    union { unsigned short us[8]; frag8 v; } o;
    o.us[0] = f2b(a[0]); o.us[1] = f2b(a[1]); o.us[2] = f2b(a[2]); o.us[3] = f2b(a[3]);
    o.us[4] = f2b(b[0]); o.us[5] = f2b(b[1]); o.us[6] = f2b(b[2]); o.us[7] = f2b(b[3]);
    *(frag8*)(dst + e) = o.v;
}

// ---------------- RoPE (in-place on q,k regions of proj) ----------------
// powf/sincosf (libm, several hundred cycles) replaced with native
// v_exp_f32 / v_sin_f32 / v_cos_f32. Phase error <= 2e-4 rad << bf16 rounding.
__global__ void rope_kernel(unsigned short* __restrict__ proj,
                            const int* __restrict__ positions) {
    int tid = blockIdx.x * 256 + threadIdx.x;   // one thread per rotation pair
    int j  = tid & 63;
    int h  = (tid >> 6) & 31;
    int qk = (tid >> 11) & 1;
    int t  = tid >> 12;                          // token index 0..4095
    int pos = positions[t];
    // 10000^(-j/64) = 2^(-j * log2(10000)/64), log2(10000)/64 = 0.20762050593
    float inv = __builtin_amdgcn_exp2f(-0.20762051f * (float)j);
    float fr = (float)pos * inv;
    float sv = __sinf(fr), cv = __cosf(fr);
    unsigned short* base = proj + (long)t * QKVN + qk * HIDDEN + h * HD;
    float x1 = b2f(base[j]);
    float x2 = b2f(base[j + 64]);
    base[j]      = f2b(x1 * cv - x2 * sv);
    base[j + 64] = f2b(x2 * cv + x1 * sv);
}

// ---------------- GEMM 256x256, BK=64, 8-phase counted-vmcnt pipeline -------
// C[M,N] = A[M,K] * B[N,K]^T, bf16 in, fp32 acc.
// 8 waves (2M x 4N), per-wave 128x64 output. LDS 128 KiB: 2 dbuf x (A 2 halves
// + B 2 halves) of [128][64] bf16. 3-bit XOR swizzle u ^= ((u>>6)&7)<<3 within
// each half (involution): applied as inverse-swizzled global SOURCE for the
// linear global_load_lds dest, and as swizzled ds_read offsets.
// vmcnt(6) = 2 loads/half x 3 halves in flight; never drains to 0 in the loop.
template <int OUT_F32>
__global__ __launch_bounds__(512, 2) void gemm256(
    const unsigned short* __restrict__ A,
    const unsigned short* __restrict__ B,
    void* __restrict__ Cv, int M, int N, int K) {
    __shared__ unsigned short lds[65536];  // 128 KiB
    const int tid = threadIdx.x, lane = tid & 63, w = tid >> 6;
    const int wr = w >> 2, wc = w & 3;
    const int fr = lane & 15, quad = lane >> 4;

    // XCD-aware bijective swizzle (nwg % 8 == 0 for both call sites)
    const int gx = gridDim.x;
    const int nwg = gx * gridDim.y;
    int bid = blockIdx.y * gx + blockIdx.x;
    const int cpx = nwg >> 3;
    int swz = (bid & 7) * cpx + (bid >> 3);
    const long n0 = (long)(swz % gx) * 256;
    const long m0 = (long)(swz / gx) * 256;

    // --- staging (inverse-swizzled global source, linear LDS dest) ---
    const int r0 = w * 8 + (lane >> 3);                  // row within 128-half, l=0
    const int scol = ((lane ^ (lane >> 3)) & 7) * 8;     // swizzled k-col (bf16)
    const int dofs = w * 512 + lane * 8;                 // ushort off within half
    const unsigned short* Ag = A + (m0 + r0) * (long)K + scol;
    const unsigned short* Bg = B + (n0 + r0) * (long)K + scol;
    auto stg = [&](unsigned short* Lh, const unsigned short* G, long t) {
        gl_lds16(G + t * 64, Lh + dofs);
        gl_lds16(G + t * 64 + (long)K * 64, Lh + dofs + 4096);
    };
#define STGA(s, h, t) stg(lds + (s)*32768 + (h)*8192, Ag + (long)(h) * 128 * K, (t))
#define STGB(s, h, t) stg(lds + (s)*32768 + 16384 + (h)*8192, Bg + (long)(h) * 128 * K, (t))

    // --- fragment read offsets (swizzled) ---
    const int qx8 = (quad ^ (fr & 3)) * 8;
    const int kx0 = (fr >> 2) & 1;
    const int arow = wr * 64 + fr;   // + mi*16 within A-half
    const int brow = wc * 32 + fr;   // + ni*16 within B-half

    frag8 af[4][2], bf0[2][2], bf1[2][2];
    fl4 acc[2][2][4][2];
    fl4 z = {0.f, 0.f, 0.f, 0.f};
#pragma unroll
    for (int qm = 0; qm < 2; ++qm)
#pragma unroll
        for (int qn = 0; qn < 2; ++qn)
#pragma unroll
            for (int mi = 0; mi < 4; ++mi)
#pragma unroll
                for (int ni = 0; ni < 2; ++ni) acc[qm][qn][mi][ni] = z;

#define LDA(h)                                                                   \
    _Pragma("unroll") for (int mi = 0; mi < 4; ++mi) {                           \
        af[mi][0] = *(const frag8*)(Lc + (h)*8192 + (arow + mi * 16) * 64 +      \
                                    (kx0 << 5) + qx8);                           \
        af[mi][1] = *(const frag8*)(Lc + (h)*8192 + (arow + mi * 16) * 64 +      \
                                    ((1 ^ kx0) << 5) + qx8);                     \
    }
#define LDB(h, BF)                                                               \
    _Pragma("unroll") for (int ni = 0; ni < 2; ++ni) {                           \
        BF[ni][0] = *(const frag8*)(Lc + 16384 + (h)*8192 +                      \
                                    (brow + ni * 16) * 64 + (kx0 << 5) + qx8);   \
        BF[ni][1] = *(const frag8*)(Lc + 16384 + (h)*8192 +                      \
                                    (brow + ni * 16) * 64 + ((1 ^ kx0) << 5) +   \
                                    qx8);                                        \
    }
#define MF(qm, qn, BF)                                                           \
    __builtin_amdgcn_s_setprio(1);                                               \
    _Pragma("unroll") for (int mi = 0; mi < 4; ++mi)                             \
        _Pragma("unroll") for (int ni = 0; ni < 2; ++ni) {                       \
        acc[qm][qn][mi][ni] = __builtin_amdgcn_mfma_f32_16x16x32_bf16(           \
            af[mi][0], BF[ni][0], acc[qm][qn][mi][ni], 0, 0, 0);                 \
        acc[qm][qn][mi][ni] = __builtin_amdgcn_mfma_f32_16x16x32_bf16(           \
            af[mi][1], BF[ni][1], acc[qm][qn][mi][ni], 0, 0, 0);                 \
    }                                                                            \
    __builtin_amdgcn_s_setprio(0);

#define KTILE(s, T)                                                              \
    {                                                                            \
        unsigned short* Lc = lds + (s)*32768;                                    \
        const long t1 = ((T) + 1 < nt) ? (T) + 1 : nt - 1;                       \
        const long t2 = ((T) + 2 < nt) ? (T) + 2 : nt - 1;                       \
        LDA(0);                                                                  \
        LDB(0, bf0);                                                             \
        STGA((s) ^ 1, 1, t1);                                                    \
        __builtin_amdgcn_s_barrier();                                            \
        asm volatile("s_waitcnt lgkmcnt(0)" ::: "memory");                       \
        MF(0, 0, bf0);                                                           \
        __builtin_amdgcn_s_barrier();                                            \
        LDB(1, bf1);                                                             \
        STGA((s), 0, t2);                                                        \
        __builtin_amdgcn_s_barrier();                                            \
        asm volatile("s_waitcnt lgkmcnt(0)" ::: "memory");                       \
        MF(0, 1, bf1);                                                           \
        __builtin_amdgcn_s_barrier();                                            \
        LDA(1);                                                                  \
        STGB((s), 0, t2);                                                        \
        __builtin_amdgcn_s_barrier();                                            \
        asm volatile("s_waitcnt lgkmcnt(0)" ::: "memory");                       \
        MF(1, 0, bf0);                                                           \
        __builtin_amdgcn_s_barrier();                                            \
        STGB((s), 1, t2);                                                        \
        asm volatile("s_waitcnt vmcnt(6)" ::: "memory");                         \
        __builtin_amdgcn_s_barrier();                                            \
        MF(1, 1, bf1);                                                           \
        __builtin_amdgcn_s_barrier();                                            \
    }

    const int nt = K >> 6;  // K-tiles of 64 (even for all call sites)
    // prologue: tile0 fully + first 3 halves of tile1 (FIFO matches steady state)
    STGA(0, 0, 0);
    STGB(0, 0, 0);
    STGB(0, 1, 0);
    STGA(0, 1, 0);
    STGA(1, 0, 1);
    STGB(1, 0, 1);
    STGB(1, 1, 1);
    asm volatile("s_waitcnt vmcnt(6)" ::: "memory");
    __builtin_amdgcn_s_barrier();

    for (int T = 0; T < nt; T += 2) {
        KTILE(0, T);
        KTILE(1, T + 1);
    }
    asm volatile("s_waitcnt vmcnt(0)" ::: "memory");

    // epilogue: C write
#pragma unroll
    for (int qm = 0; qm < 2; ++qm)
#pragma unroll
        for (int qn = 0; qn < 2; ++qn)
#pragma unroll
            for (int mi = 0; mi < 4; ++mi)
#pragma unroll
                for (int ni = 0; ni < 2; ++ni)
#pragma unroll
                    for (int r = 0; r < 4; ++r) {
                        long row = m0 + qm * 128 + wr * 64 + mi * 16 + quad * 4 + r;
                        long col = n0 + qn * 128 + wc * 32 + ni * 16 + fr;
                        float v = acc[qm][qn][mi][ni][r];
                        if (OUT_F32)
                            ((float*)Cv)[row * N + col] = v;
                        else
                            ((unsigned short*)Cv)[row * N + col] = f2b(v);
                    }
#undef STGA
#undef STGB
#undef LDA
#undef LDB
#undef MF
#undef KTILE
}

// ---------------- causal flash attention ----------------
// block = (q-tile of 128) x head x batch; 4 waves, each owns 32 q rows.
// K-tile = 64 keys/iter. Q frags live in registers (loaded once from global).
// SWAPPED QK^T: S^T = mfma(K, Q) puts q on the C column (lane-local) ->
// row-softmax = in-lane fmax + 2 cross-quad shfls (was 64 shfls/tile).
// m/l state is per-lane (q = fr); O-rescale alphas redistributed by shfls,
// gated by defer-max (THR=8) so it runs ~once per q-block.
__global__ __launch_bounds__(256, 2) void attn_kernel(
    const unsigned short* __restrict__ proj,   // [NTOK, 12288], rope'd
    unsigned short* __restrict__ out) {        // [NTOK, 4096]
    __shared__ unsigned short Ks[64 * 128];    // [k][d], XOR chunk swizzle
    __shared__ unsigned short Vt[128 * 80];    // [d][k], stride 80
    __shared__ unsigned short Ps[4][32 * 88];  // per-wave P, stride 88

    const int qt = (int)gridDim.x - 1 - (int)blockIdx.x;  // big tiles first
    const int h = blockIdx.y;
    const int b = blockIdx.z;
    const int tid = threadIdx.x, lane = tid & 63, w = tid >> 6;
    const int q0 = qt * 128;
    const int fr = lane & 15, quad = lane >> 4;
    const int fq = quad * 8;
    const long tokbase = (long)b * SEQ;
    const float scale = 0.08838834764831845f;  // 1/sqrt(128)
    fl4 z = {0.f, 0.f, 0.f, 0.f};

    // Q fragments: rows q0 + w*32 + mi*16 + fr (A/B frag layouts are identical)
    frag8 qf[2][4];
#pragma unroll
    for (int mi = 0; mi < 2; mi++)
#pragma unroll
        for (int kc = 0; kc < 4; kc++) {
            int qrow = q0 + w * 32 + mi * 16 + fr;
            qf[mi][kc] = *(const frag8*)(proj + (tokbase + qrow) * QKVN +
                                         h * HD + kc * 32 + fq);
        }

    fl4 o[2][8];
#pragma unroll
    for (int mi = 0; mi < 2; mi++)
#pragma unroll
        for (int n = 0; n < 8; n++) o[mi][n] = z;
    // per-lane softmax state for q = q0 + w*32 + mi*16 + fr
    float m_i[2], l_i[2];
    m_i[0] = m_i[1] = -1e30f;
    l_i[0] = l_i[1] = 0.f;

    // K staging: LDS row = c*16 + w*4 + (lane>>4); phys chunk lane&15;
    // XOR swizzle phys[r][c] = logical[r][c ^ (r&15)]
    const int ksrow = w * 4 + (lane >> 4);
    const int kphys = (lane & 15) * 8;
    const int kgcol = ((lane & 15) ^ ksrow) * 8;
    // V staging (transpose): thread -> (row=lane, dchunk=w*32)
    const int vrow = lane;
    const int vdc = w * 32;

    const int ktiles = (q0 + 128) / 64;
    for (int kt = 0; kt < ktiles; kt++) {
        const int k0 = kt * 64;
        __syncthreads();
#pragma unroll
        for (int c = 0; c < 4; c++) {
            long tok = tokbase + k0 + c * 16 + ksrow;
            gl_lds16(proj + tok * QKVN + HIDDEN + h * HD + kgcol,
                     Ks + (c * 16 + ksrow) * 128 + kphys);
        }
        {
            const unsigned short* vp =
                proj + (tokbase + k0 + vrow) * QKVN + 2 * HIDDEN + h * HD + vdc;
#pragma unroll
            for (int u = 0; u < 4; u++) {
                frag8 vv = *(const frag8*)(vp + u * 8);
#pragma unroll
                for (int e = 0; e < 8; e++)
                    Vt[(vdc + u * 8 + e) * 80 + vrow] = (unsigned short)vv[e];
            }
        }
        __syncthreads();

        // S^T = K Q^T : C row = k-sub (quad*4+r), col = q (fr)
        fl4 sc[2][4];
#pragma unroll
        for (int kn = 0; kn < 4; kn++) {
            frag8 kf[4];
#pragma unroll
            for (int kc = 0; kc < 4; kc++)
                kf[kc] = *(const frag8*)(Ks + (kn * 16 + fr) * 128 +
                                         ((kc * 4 + quad) ^ fr) * 8);
#pragma unroll
            for (int mi = 0; mi < 2; mi++) {
                fl4 a = z;
#pragma unroll
                for (int kc = 0; kc < 4; kc++)
                    a = __builtin_amdgcn_mfma_f32_16x16x32_bf16(kf[kc],
                                                                qf[mi][kc], a, 0, 0, 0);
                sc[mi][kn] = a;
            }
        }

        // ---- in-register online softmax (per-lane rows) ----
        float mx2[2];
#pragma unroll
        for (int mi = 0; mi < 2; mi++) {
            const int qrow = q0 + w * 32 + mi * 16 + fr;
            float mxv = -1e30f;
#pragma unroll
            for (int kn = 0; kn < 4; kn++) {
                const int kbase = k0 + kn * 16 + quad * 4;
#pragma unroll
                for (int r = 0; r < 4; r++) {
                    float s = sc[mi][kn][r] * scale;
                    s = (kbase + r <= qrow) ? s : -1e30f;
                    sc[mi][kn][r] = s;
                    mxv = fmaxf(mxv, s);
                }
            }
            mxv = fmaxf(mxv, __shfl_xor(mxv, 16, 64));
            mxv = fmaxf(mxv, __shfl_xor(mxv, 32, 64));
            mx2[mi] = mxv;
        }
        // defer-max: rescale only when max grows past THR=8 (wave-uniform)
        bool need = (mx2[0] > m_i[0] + 8.0f) || (mx2[1] > m_i[1] + 8.0f);
        if (__any(need)) {
            float alpha[2];
#pragma unroll
            for (int mi = 0; mi < 2; mi++) {
                float mnew = fmaxf(m_i[mi], mx2[mi]);
                alpha[mi] = __expf(m_i[mi] - mnew);
                m_i[mi] = mnew;
                l_i[mi] *= alpha[mi];
            }
#pragma unroll
            for (int mi = 0; mi < 2; mi++)
#pragma unroll
                for (int rr = 0; rr < 4; rr++) {
                    float af = __shfl(alpha[mi], (lane & 48) | (quad * 4 + rr), 64);
#pragma unroll
                    for (int n = 0; n < 8; n++) o[mi][n][rr] *= af;
                }
        }
        // P = exp(S - m), pack to bf16, store b64 runs of 4 consecutive k
#pragma unroll
        for (int mi = 0; mi < 2; mi++) {
            float rsum = 0.f;
            const float m = m_i[mi];
#pragma unroll
            for (int kn = 0; kn < 4; kn++) {
                union { unsigned short us[4]; unsigned long long u; } pk;
#pragma unroll
                for (int r = 0; r < 4; r++) {
                    float p = __expf(sc[mi][kn][r] - m);
                    pk.us[r] = f2b(p);
                    rsum += b2f(pk.us[r]);
                }
                *(unsigned long long*)(&Ps[w][(mi * 16 + fr) * 88 + kn * 16 +
                                              quad * 4]) = pk.u;
            }
            rsum += __shfl_xor(rsum, 16, 64);
            rsum += __shfl_xor(rsum, 32, 64);
            l_i[mi] += rsum;
        }

        // O += P V   (P round-trips LDS: [q][k] -> A-layout; per-wave, no barrier)
        frag8 pf[2][2];
#pragma unroll
        for (int mi = 0; mi < 2; mi++)
#pragma unroll
            for (int kc = 0; kc < 2; kc++)
                pf[mi][kc] =
                    *(const frag8*)(Ps[w] + (mi * 16 + fr) * 88 + kc * 32 + fq);
#pragma unroll
        for (int n = 0; n < 8; n++) {
            frag8 vf0 = *(const frag8*)(Vt + (n * 16 + fr) * 80 + fq);
            frag8 vf1 = *(const frag8*)(Vt + (n * 16 + fr) * 80 + 32 + fq);
#pragma unroll
            for (int mi = 0; mi < 2; mi++) {
                o[mi][n] = __builtin_amdgcn_mfma_f32_16x16x32_bf16(pf[mi][0], vf0,
                                                                   o[mi][n], 0, 0, 0);
                o[mi][n] = __builtin_amdgcn_mfma_f32_16x16x32_bf16(pf[mi][1], vf1,
                                                                   o[mi][n], 0, 0, 0);
            }
        }
    }
    // epilogue: O / l -> out[tok][h*128 + d]; l redistributed by shfl
#pragma unroll
    for (int mi = 0; mi < 2; mi++)
#pragma unroll
        for (int rr = 0; rr < 4; rr++) {
            float lf = __shfl(l_i[mi], (lane & 48) | (quad * 4 + rr), 64);
            float rl = 1.0f / lf;
            int qrow = q0 + w * 32 + mi * 16 + quad * 4 + rr;
#pragma unroll
            for (int n = 0; n < 8; n++)
                out[(tokbase + qrow) * HIDDEN + h * HD + n * 16 + fr] =
                    f2b(o[mi][n][rr] * rl);
        }
}

extern "C" void kernel_launch(void* const* d_in, const int* in_sizes, int n_in,
                              void* d_out, int out_size, void* d_ws, size_t ws_size,
                              hipStream_t stream) {
    const float* hs = (const float*)d_in[0];   // [2,2048,4096]
    const int* pos  = (const int*)d_in[1];     // [2,2048]
    const float* wp = (const float*)d_in[2];   // [12288,4096]
    const float* wo = (const float*)d_in[3];   // [4096,4096]
    float* out = (float*)d_out;                // [2,2048,4096] fp32

    char* ws = (char*)d_ws;
    unsigned short* Xb    = (unsigned short*)ws;                 // 32 MB
    unsigned short* Wpb   = (unsigned short*)(ws + 33554432L);   // 96 MB
    unsigned short* proj  = (unsigned short*)(ws + 134217728L);  // 96 MB
    unsigned short* attnb = Wpb;  // reuse after gemm1
    unsigned short* Wob   = Xb;   // reuse after gemm1

    cvt_f32_bf16<<<(16777216 / 8) / 256, 256, 0, stream>>>(hs, Xb, 16777216 / 8);
    cvt_f32_bf16<<<(50331648 / 8) / 256, 256, 0, stream>>>(wp, Wpb, 50331648 / 8);
    gemm256<0><<<dim3(QKVN / 256, NTOK / 256), 512, 0, stream>>>(
        Xb, Wpb, (void*)proj, NTOK, QKVN, HIDDEN);
    rope_kernel<<<16777216 / 256, 256, 0, stream>>>(proj, pos);
    attn_kernel<<<dim3(SEQ / 128, NHEADS, 2), 256, 0, stream>>>(proj, attnb);
    cvt_f32_bf16<<<(16777216 / 8) / 256, 256, 0, stream>>>(wo, Wob, 16777216 / 8);
    gemm256<1><<<dim3(HIDDEN / 256, NTOK / 256), 512, 0, stream>>>(
        attnb, Wob, d_out, NTOK, HIDDEN, HIDDEN);
}

// Round 5
// 1042.418 us; speedup vs baseline: 1.3945x; 1.0470x over previous
//
#include <hip/hip_runtime.h>
#include <stdint.h>

#define HIDDEN 4096
#define NHEADS 32
#define HD 128
#define SEQ 2048
#define NTOK 4096
#define QKVN 12288

typedef __attribute__((ext_vector_type(8))) short frag8;
typedef __attribute__((ext_vector_type(4))) float fl4;

__device__ __forceinline__ unsigned short f2b(float f) {
    unsigned u = __float_as_uint(f);
    return (unsigned short)((u + 0x7FFFu + ((u >> 16) & 1u)) >> 16);
}
__device__ __forceinline__ float b2f(unsigned short h) {
    return __uint_as_float(((unsigned)h) << 16);
}
// async global->LDS, 16B per lane. LDS dest is wave-uniform base + lane*16.
__device__ __forceinline__ void gl_lds16(const void* g, void* l) {
    __builtin_amdgcn_global_load_lds(
        (const __attribute__((address_space(1))) unsigned int*)(uintptr_t)g,
        (__attribute__((address_space(3))) unsigned int*)(uintptr_t)l,
        16, 0, 0);
}

// ---------------- fp32 -> bf16 conversion ----------------
__global__ void cvt_f32_bf16(const float* __restrict__ src,
                             unsigned short* __restrict__ dst, int n8) {
    int i = blockIdx.x * 256 + threadIdx.x;
    if (i >= n8) return;
    long e = (long)i * 8;
    fl4 a = *(const fl4*)(src + e);
    fl4 b = *(const fl4*)(src + e + 4);
    union { unsigned short us[8]; frag8 v; } o;
    o.us[0] = f2b(a[0]); o.us[1] = f2b(a[1]); o.us[2] = f2b(a[2]); o.us[3] = f2b(a[3]);
    o.us[4] = f2b(b[0]); o.us[5] = f2b(b[1]); o.us[6] = f2b(b[2]); o.us[7] = f2b(b[3]);
    *(frag8*)(dst + e) = o.v;
}

// ---------------- RoPE (in-place on q,k regions of proj) ----------------
__global__ void rope_kernel(unsigned short* __restrict__ proj,
                            const int* __restrict__ positions) {
    int tid = blockIdx.x * 256 + threadIdx.x;   // one thread per rotation pair
    int j  = tid & 63;
    int h  = (tid >> 6) & 31;
    int qk = (tid >> 11) & 1;
    int t  = tid >> 12;                          // token index 0..4095
    int pos = positions[t];
    // 10000^(-j/64) = 2^(-j * log2(10000)/64)
    float inv = __builtin_amdgcn_exp2f(-0.20762051f * (float)j);
    float fr = (float)pos * inv;
    float sv = __sinf(fr), cv = __cosf(fr);
    unsigned short* base = proj + (long)t * QKVN + qk * HIDDEN + h * HD;
    float x1 = b2f(base[j]);
    float x2 = b2f(base[j + 64]);
    base[j]      = f2b(x1 * cv - x2 * sv);
    base[j + 64] = f2b(x2 * cv + x1 * sv);
}

// ---------------- GEMM 256x256, BK=64, 8-phase counted-vmcnt pipeline -------
// C[M,N] = A[M,K] * B[N,K]^T, bf16 in, fp32 acc.
// XCD mapping: each XCD gets a contiguous tile range, tiled as 4m x 8n
// supertiles of 32 blocks -> per-K-slice L2 working set 12 panels (384 KB)
// instead of 33 (row-strip), cutting L2-miss FETCH.
template <int OUT_F32>
__global__ __launch_bounds__(512, 2) void gemm256(
    const unsigned short* __restrict__ A,
    const unsigned short* __restrict__ B,
    void* __restrict__ Cv, int M, int N, int K) {
    __shared__ unsigned short lds[65536];  // 128 KiB
    const int tid = threadIdx.x, lane = tid & 63, w = tid >> 6;
    const int wr = w >> 2, wc = w & 3;
    const int fr = lane & 15, quad = lane >> 4;

    // XCD-aware bijective swizzle + 4x8 supertile chunking
    // (requires nwg%32==0, gy%4==0, gx%8==0 -- true for both call sites)
    const int gx = gridDim.x;
    const int gy = gridDim.y;
    const int nwg = gx * gy;
    int bid = blockIdx.y * gx + blockIdx.x;
    const int cpx = nwg >> 3;
    int u = (bid & 7) * cpx + (bid >> 3);   // per-XCD contiguous tile index
    int chunk = u >> 5, j = u & 31;
    const int gy4 = gy >> 2;
    const long m0 = (long)((chunk % gy4) * 4 + (j >> 3)) * 256;
    const long n0 = (long)((chunk / gy4) * 8 + (j & 7)) * 256;

    // --- staging (inverse-swizzled global source, linear LDS dest) ---
    const int r0 = w * 8 + (lane >> 3);                  // row within 128-half
    const int scol = ((lane ^ (lane >> 3)) & 7) * 8;     // swizzled k-col (bf16)
    const int dofs = w * 512 + lane * 8;                 // ushort off within half
    const unsigned short* Ag = A + (m0 + r0) * (long)K + scol;
    const unsigned short* Bg = B + (n0 + r0) * (long)K + scol;
    auto stg = [&](unsigned short* Lh, const unsigned short* G, long t) {
        gl_lds16(G + t * 64, Lh + dofs);
        gl_lds16(G + t * 64 + (long)K * 64, Lh + dofs + 4096);
    };
#define STGA(s, h, t) stg(lds + (s)*32768 + (h)*8192, Ag + (long)(h) * 128 * K, (t))
#define STGB(s, h, t) stg(lds + (s)*32768 + 16384 + (h)*8192, Bg + (long)(h) * 128 * K, (t))

    // --- fragment read offsets (swizzled) ---
    const int qx8 = (quad ^ (fr & 3)) * 8;
    const int kx0 = (fr >> 2) & 1;
    const int arow = wr * 64 + fr;   // + mi*16 within A-half
    const int brow = wc * 32 + fr;   // + ni*16 within B-half

    frag8 af[4][2], bf0[2][2], bf1[2][2];
    fl4 acc[2][2][4][2];
    fl4 z = {0.f, 0.f, 0.f, 0.f};
#pragma unroll
    for (int qm = 0; qm < 2; ++qm)
#pragma unroll
        for (int qn = 0; qn < 2; ++qn)
#pragma unroll
            for (int mi = 0; mi < 4; ++mi)
#pragma unroll
                for (int ni = 0; ni < 2; ++ni) acc[qm][qn][mi][ni] = z;

#define LDA(h)                                                                   \
    _Pragma("unroll") for (int mi = 0; mi < 4; ++mi) {                           \
        af[mi][0] = *(const frag8*)(Lc + (h)*8192 + (arow + mi * 16) * 64 +      \
                                    (kx0 << 5) + qx8);                           \
        af[mi][1] = *(const frag8*)(Lc + (h)*8192 + (arow + mi * 16) * 64 +      \
                                    ((1 ^ kx0) << 5) + qx8);                     \
    }
#define LDB(h, BF)                                                               \
    _Pragma("unroll") for (int ni = 0; ni < 2; ++ni) {                           \
        BF[ni][0] = *(const frag8*)(Lc + 16384 + (h)*8192 +                      \
                                    (brow + ni * 16) * 64 + (kx0 << 5) + qx8);   \
        BF[ni][1] = *(const frag8*)(Lc + 16384 + (h)*8192 +                      \
                                    (brow + ni * 16) * 64 + ((1 ^ kx0) << 5) +   \
                                    qx8);                                        \
    }
#define MF(qm, qn, BF)                                                           \
    __builtin_amdgcn_s_setprio(1);                                               \
    _Pragma("unroll") for (int mi = 0; mi < 4; ++mi)                             \
        _Pragma("unroll") for (int ni = 0; ni < 2; ++ni) {                       \
        acc[qm][qn][mi][ni] = __builtin_amdgcn_mfma_f32_16x16x32_bf16(           \
            af[mi][0], BF[ni][0], acc[qm][qn][mi][ni], 0, 0, 0);                 \
        acc[qm][qn][mi][ni] = __builtin_amdgcn_mfma_f32_16x16x32_bf16(           \
            af[mi][1], BF[ni][1], acc[qm][qn][mi][ni], 0, 0, 0);                 \
    }                                                                            \
    __builtin_amdgcn_s_setprio(0);

#define KTILE(s, T)                                                              \
    {                                                                            \
        unsigned short* Lc = lds + (s)*32768;                                    \
        const long t1 = ((T) + 1 < nt) ? (T) + 1 : nt - 1;                       \
        const long t2 = ((T) + 2 < nt) ? (T) + 2 : nt - 1;                       \
        LDA(0);                                                                  \
        LDB(0, bf0);                                                             \
        STGA((s) ^ 1, 1, t1);                                                    \
        __builtin_amdgcn_s_barrier();                                            \
        asm volatile("s_waitcnt lgkmcnt(0)" ::: "memory");                       \
        MF(0, 0, bf0);                                                           \
        __builtin_amdgcn_s_barrier();                                            \
        LDB(1, bf1);                                                             \
        STGA((s), 0, t2);                                                        \
        __builtin_amdgcn_s_barrier();                                            \
        asm volatile("s_waitcnt lgkmcnt(0)" ::: "memory");                       \
        MF(0, 1, bf1);                                                           \
        __builtin_amdgcn_s_barrier();                                            \
        LDA(1);                                                                  \
        STGB((s), 0, t2);                                                        \
        __builtin_amdgcn_s_barrier();                                            \
        asm volatile("s_waitcnt lgkmcnt(0)" ::: "memory");                       \
        MF(1, 0, bf0);                                                           \
        __builtin_amdgcn_s_barrier();                                            \
        STGB((s), 1, t2);                                                        \
        asm volatile("s_waitcnt vmcnt(6)" ::: "memory");                         \
        __builtin_amdgcn_s_barrier();                                            \
        MF(1, 1, bf1);                                                           \
        __builtin_amdgcn_s_barrier();                                            \
    }

    const int nt = K >> 6;  // K-tiles of 64 (even for all call sites)
    // prologue: tile0 fully + first 3 halves of tile1 (FIFO matches steady state)
    STGA(0, 0, 0);
    STGB(0, 0, 0);
    STGB(0, 1, 0);
    STGA(0, 1, 0);
    STGA(1, 0, 1);
    STGB(1, 0, 1);
    STGB(1, 1, 1);
    asm volatile("s_waitcnt vmcnt(6)" ::: "memory");
    __builtin_amdgcn_s_barrier();

    for (int T = 0; T < nt; T += 2) {
        KTILE(0, T);
        KTILE(1, T + 1);
    }
    asm volatile("s_waitcnt vmcnt(0)" ::: "memory");

    // epilogue: C write
#pragma unroll
    for (int qm = 0; qm < 2; ++qm)
#pragma unroll
        for (int qn = 0; qn < 2; ++qn)
#pragma unroll
            for (int mi = 0; mi < 4; ++mi)
#pragma unroll
                for (int ni = 0; ni < 2; ++ni)
#pragma unroll
                    for (int r = 0; r < 4; ++r) {
                        long row = m0 + qm * 128 + wr * 64 + mi * 16 + quad * 4 + r;
                        long col = n0 + qn * 128 + wc * 32 + ni * 16 + fr;
                        float v = acc[qm][qn][mi][ni][r];
                        if (OUT_F32)
                            ((float*)Cv)[row * N + col] = v;
                        else
                            ((unsigned short*)Cv)[row * N + col] = f2b(v);
                    }
#undef STGA
#undef STGB
#undef LDA
#undef LDB
#undef MF
#undef KTILE
}

// ---------------- causal flash attention ----------------
// block = (q-tile of 128) x head x batch; 4 waves, each owns 32 q rows.
// SWAPPED QK^T (in-lane softmax) + defer-max, as round 4. NEW this round:
// K double-buffered; K(t+1) gl_lds + V(t+1) global->reg loads issued BEFORE
// computing tile t; raw s_barrier + lgkmcnt(0) (loads stay in flight across
// the barrier); single vmcnt(0) at tile end where compute covered latency.
__global__ __launch_bounds__(256, 2) void attn_kernel(
    const unsigned short* __restrict__ proj,   // [NTOK, 12288], rope'd
    unsigned short* __restrict__ out) {        // [NTOK, 4096]
    __shared__ unsigned short Ks[2][64 * 128]; // [k][d], XOR chunk swizzle, dbuf
    __shared__ unsigned short Vt[128 * 82];    // [d][k], stride 82 (bank-clean)
    __shared__ unsigned short Ps[4][32 * 88];  // per-wave P, stride 88

    const int qt = (int)gridDim.x - 1 - (int)blockIdx.x;  // big tiles first
    const int h = blockIdx.y;
    const int b = blockIdx.z;
    const int tid = threadIdx.x, lane = tid & 63, w = tid >> 6;
    const int q0 = qt * 128;
    const int fr = lane & 15, quad = lane >> 4;
    const int fq = quad * 8;
    const long tokbase = (long)b * SEQ;
    const float scale = 0.08838834764831845f;  // 1/sqrt(128)
    fl4 z = {0.f, 0.f, 0.f, 0.f};

    // Q fragments: rows q0 + w*32 + mi*16 + fr
    frag8 qf[2][4];
#pragma unroll
    for (int mi = 0; mi < 2; mi++)
#pragma unroll
        for (int kc = 0; kc < 4; kc++) {
            int qrow = q0 + w * 32 + mi * 16 + fr;
            qf[mi][kc] = *(const frag8*)(proj + (tokbase + qrow) * QKVN +
                                         h * HD + kc * 32 + fq);
        }

    fl4 o[2][8];
#pragma unroll
    for (int mi = 0; mi < 2; mi++)
#pragma unroll
        for (int n = 0; n < 8; n++) o[mi][n] = z;
    float m_i[2], l_i[2];
    m_i[0] = m_i[1] = -1e30f;
    l_i[0] = l_i[1] = 0.f;

    // K staging: XOR swizzle phys[r][c] = logical[r][c ^ (r&15)]
    const int ksrow = w * 4 + (lane >> 4);
    const int kphys = (lane & 15) * 8;
    const int kgcol = ((lane & 15) ^ ksrow) * 8;
    // V staging (transpose): thread -> (row=lane, dchunk=w*32)
    const int vrow = lane;
    const int vdc = w * 32;

    const int ktiles = (q0 + 128) / 64;

    frag8 vva[4], vvb[4];
    // prologue: stage tile 0
    {
#pragma unroll
        for (int c = 0; c < 4; c++) {
            long tok = tokbase + 0 + c * 16 + ksrow;
            gl_lds16(proj + tok * QKVN + HIDDEN + h * HD + kgcol,
                     Ks[0] + (c * 16 + ksrow) * 128 + kphys);
        }
        const unsigned short* vp =
            proj + (tokbase + 0 + vrow) * QKVN + 2 * HIDDEN + h * HD + vdc;
#pragma unroll
        for (int u = 0; u < 4; u++) vva[u] = *(const frag8*)(vp + u * 8);
    }
    asm volatile("s_waitcnt vmcnt(0)" ::: "memory");
    __builtin_amdgcn_s_barrier();

    int cur = 0;
    for (int kt = 0; kt < ktiles; kt++) {
        const int k0 = kt * 64;
        // V(t) regs -> Vt
#pragma unroll
        for (int u = 0; u < 4; u++)
#pragma unroll
            for (int e = 0; e < 8; e++)
                Vt[(vdc + u * 8 + e) * 82 + vrow] = (unsigned short)vva[u][e];
        // prefetch tile t+1 (clamped on last tile; results unused)
        {
            const int nk0 = (kt + 1 < ktiles) ? (kt + 1) * 64 : kt * 64;
#pragma unroll
            for (int c = 0; c < 4; c++) {
                long tok = tokbase + nk0 + c * 16 + ksrow;
                gl_lds16(proj + tok * QKVN + HIDDEN + h * HD + kgcol,
                         Ks[cur ^ 1] + (c * 16 + ksrow) * 128 + kphys);
            }
            const unsigned short* vp =
                proj + (tokbase + nk0 + vrow) * QKVN + 2 * HIDDEN + h * HD + vdc;
#pragma unroll
            for (int u = 0; u < 4; u++) vvb[u] = *(const frag8*)(vp + u * 8);
        }
        // Vt visible to all waves; K(t+1)/V(t+1) stay in flight
        asm volatile("s_waitcnt lgkmcnt(0)" ::: "memory");
        __builtin_amdgcn_s_barrier();

        // S^T = K Q^T : C row = k-sub (quad*4+r), col = q (fr)
        fl4 sc[2][4];
#pragma unroll
        for (int kn = 0; kn < 4; kn++) {
            frag8 kf[4];
#pragma unroll
            for (int kc = 0; kc < 4; kc++)
                kf[kc] = *(const frag8*)(Ks[cur] + (kn * 16 + fr) * 128 +
                                         ((kc * 4 + quad) ^ fr) * 8);
#pragma unroll
            for (int mi = 0; mi < 2; mi++) {
                fl4 a = z;
#pragma unroll
                for (int kc = 0; kc < 4; kc++)
                    a = __builtin_amdgcn_mfma_f32_16x16x32_bf16(kf[kc],
                                                                qf[mi][kc], a, 0, 0, 0);
                sc[mi][kn] = a;
            }
        }

        // ---- in-register online softmax (per-lane rows) ----
        float mx2[2];
#pragma unroll
        for (int mi = 0; mi < 2; mi++) {
            const int qrow = q0 + w * 32 + mi * 16 + fr;
            float mxv = -1e30f;
#pragma unroll
            for (int kn = 0; kn < 4; kn++) {
                const int kbase = k0 + kn * 16 + quad * 4;
#pragma unroll
                for (int r = 0; r < 4; r++) {
                    float s = sc[mi][kn][r] * scale;
                    s = (kbase + r <= qrow) ? s : -1e30f;
                    sc[mi][kn][r] = s;
                    mxv = fmaxf(mxv, s);
                }
            }
            mxv = fmaxf(mxv, __shfl_xor(mxv, 16, 64));
            mxv = fmaxf(mxv, __shfl_xor(mxv, 32, 64));
            mx2[mi] = mxv;
        }
        // defer-max: rescale only when max grows past THR=8 (wave-uniform)
        bool need = (mx2[0] > m_i[0] + 8.0f) || (mx2[1] > m_i[1] + 8.0f);
        if (__any(need)) {
            float alpha[2];
#pragma unroll
            for (int mi = 0; mi < 2; mi++) {
                float mnew = fmaxf(m_i[mi], mx2[mi]);
                alpha[mi] = __expf(m_i[mi] - mnew);
                m_i[mi] = mnew;
                l_i[mi] *= alpha[mi];
            }
#pragma unroll
            for (int mi = 0; mi < 2; mi++)
#pragma unroll
                for (int rr = 0; rr < 4; rr++) {
                    float af = __shfl(alpha[mi], (lane & 48) | (quad * 4 + rr), 64);
#pragma unroll
                    for (int n = 0; n < 8; n++) o[mi][n][rr] *= af;
                }
        }
        // P = exp(S - m), pack to bf16, store b64 runs of 4 consecutive k
#pragma unroll
        for (int mi = 0; mi < 2; mi++) {
            float rsum = 0.f;
            const float m = m_i[mi];
#pragma unroll
            for (int kn = 0; kn < 4; kn++) {
                union { unsigned short us[4]; unsigned long long u; } pk;
#pragma unroll
                for (int r = 0; r < 4; r++) {
                    float p = __expf(sc[mi][kn][r] - m);
                    pk.us[r] = f2b(p);
                    rsum += b2f(pk.us[r]);
                }
                *(unsigned long long*)(&Ps[w][(mi * 16 + fr) * 88 + kn * 16 +
                                              quad * 4]) = pk.u;
            }
            rsum += __shfl_xor(rsum, 16, 64);
            rsum += __shfl_xor(rsum, 32, 64);
            l_i[mi] += rsum;
        }

        // O += P V   (P round-trips LDS: [q][k] -> A-layout; per-wave, no barrier)
        frag8 pf[2][2];
#pragma unroll
        for (int mi = 0; mi < 2; mi++)
#pragma unroll
            for (int kc = 0; kc < 2; kc++)
                pf[mi][kc] =
                    *(const frag8*)(Ps[w] + (mi * 16 + fr) * 88 + kc * 32 + fq);
#pragma unroll
        for (int n = 0; n < 8; n++) {
            frag8 vf0 = *(const frag8*)(Vt + (n * 16 + fr) * 82 + fq);
            frag8 vf1 = *(const frag8*)(Vt + (n * 16 + fr) * 82 + 32 + fq);
#pragma unroll
            for (int mi = 0; mi < 2; mi++) {
                o[mi][n] = __builtin_amdgcn_mfma_f32_16x16x32_bf16(pf[mi][0], vf0,
                                                                   o[mi][n], 0, 0, 0);
                o[mi][n] = __builtin_amdgcn_mfma_f32_16x16x32_bf16(pf[mi][1], vf1,
                                                                   o[mi][n], 0, 0, 0);
            }
        }
        // drain prefetch (latency already covered by compute) + tile barrier
        asm volatile("s_waitcnt vmcnt(0)" ::: "memory");
        __builtin_amdgcn_s_barrier();
        cur ^= 1;
#pragma unroll
        for (int u = 0; u < 4; u++) vva[u] = vvb[u];
    }
    // epilogue: O / l -> out[tok][h*128 + d]; l redistributed by shfl
#pragma unroll
    for (int mi = 0; mi < 2; mi++)
#pragma unroll
        for (int rr = 0; rr < 4; rr++) {
            float lf = __shfl(l_i[mi], (lane & 48) | (quad * 4 + rr), 64);
            float rl = 1.0f / lf;
            int qrow = q0 + w * 32 + mi * 16 + quad * 4 + rr;
#pragma unroll
            for (int n = 0; n < 8; n++)
                out[(tokbase + qrow) * HIDDEN + h * HD + n * 16 + fr] =
                    f2b(o[mi][n][rr] * rl);
        }
}

extern "C" void kernel_launch(void* const* d_in, const int* in_sizes, int n_in,
                              void* d_out, int out_size, void* d_ws, size_t ws_size,
                              hipStream_t stream) {
    const float* hs = (const float*)d_in[0];   // [2,2048,4096]
    const int* pos  = (const int*)d_in[1];     // [2,2048]
    const float* wp = (const float*)d_in[2];   // [12288,4096]
    const float* wo = (const float*)d_in[3];   // [4096,4096]
    float* out = (float*)d_out;                // [2,2048,4096] fp32

    char* ws = (char*)d_ws;
    unsigned short* Xb    = (unsigned short*)ws;                 // 32 MB
    unsigned short* Wpb   = (unsigned short*)(ws + 33554432L);   // 96 MB
    unsigned short* proj  = (unsigned short*)(ws + 134217728L);  // 96 MB
    unsigned short* attnb = Wpb;  // reuse after gemm1
    unsigned short* Wob   = Xb;   // reuse after gemm1

    cvt_f32_bf16<<<(16777216 / 8) / 256, 256, 0, stream>>>(hs, Xb, 16777216 / 8);
    cvt_f32_bf16<<<(50331648 / 8) / 256, 256, 0, stream>>>(wp, Wpb, 50331648 / 8);
    gemm256<0><<<dim3(QKVN / 256, NTOK / 256), 512, 0, stream>>>(
        Xb, Wpb, (void*)proj, NTOK, QKVN, HIDDEN);
    rope_kernel<<<16777216 / 256, 256, 0, stream>>>(proj, pos);
    attn_kernel<<<dim3(SEQ / 128, NHEADS, 2), 256, 0, stream>>>(proj, attnb);
    cvt_f32_bf16<<<(16777216 / 8) / 256, 256, 0, stream>>>(wo, Wob, 16777216 / 8);
    gemm256<1><<<dim3(HIDDEN / 256, NTOK / 256), 512, 0, stream>>>(
        attnb, Wob, d_out, NTOK, HIDDEN, HIDDEN);
}